// Round 2
// baseline (443.593 us; speedup 1.0000x reference)
//
#include <hip/hip_runtime.h>

// EMA: y[0]=x[0]; y[t] = s*x[t] + (1-s)*y[t-1],  s=0.3, shape (B,T,D)=(64,4096,256)
// f32 in/out (round-1 evidence: bf16 cast gave max-scale error => buffers are f32).
// Constant decay 0.7 => 0.7^32 ~ 1e-5, so T-chunks are independent given a
// 32-step warm-up: embarrassingly parallel single pass, 12.5% read overhead.
// Memory-bound floor ~86us (544 MiB at 6.3 TB/s).

constexpr int   Bc = 64;
constexpr int   Tc = 4096;
constexpr int   Dc = 256;
constexpr float S  = 0.3f;
constexpr float R  = 1.0f - S;

constexpr int L  = 256;        // chunk length along T
constexpr int W  = 32;         // warm-up steps (0.7^33 ~ 7e-6 relative error)
constexpr int DP = Dc / 2;     // 128 float2 per row
constexpr int NC = Tc / L;     // 16 chunks

__global__ __launch_bounds__(256)
void ema_f32_kernel(const float2* __restrict__ x,
                    float2* __restrict__ y)
{
    const int tid = blockIdx.x * 256 + threadIdx.x;
    const int dp  = tid & (DP - 1);          // d-pair index  [0,128)
    const int c   = (tid >> 7) & (NC - 1);   // chunk index   [0,16)
    const int b   = tid >> 11;               // batch index   [0,64)
    const int t0  = c * L;
    const long base = (long)b * Tc * DP + dp;  // float2-element index at t=0

    float y0 = 0.0f, y1 = 0.0f;
    int tstart = t0;

    if (c == 0) {
        // exact init: y[0] = x[0]
        float2 v = x[base];
        y0 = v.x;
        y1 = v.y;
        y[base] = v;
        tstart = 1;
    } else {
        // warm-up from zero init, W steps before the chunk
        #pragma unroll
        for (int t = t0 - W; t < t0; ++t) {
            float2 v = x[base + (long)t * DP];
            y0 = fmaf(R, y0, S * v.x);
            y1 = fmaf(R, y1, S * v.y);
        }
    }

    #pragma unroll 8
    for (int t = tstart; t < t0 + L; ++t) {
        float2 v = x[base + (long)t * DP];
        y0 = fmaf(R, y0, S * v.x);
        y1 = fmaf(R, y1, S * v.y);
        float2 o;
        o.x = y0;
        o.y = y1;
        y[base + (long)t * DP] = o;
    }
}

extern "C" void kernel_launch(void* const* d_in, const int* in_sizes, int n_in,
                              void* d_out, int out_size, void* d_ws, size_t ws_size,
                              hipStream_t stream) {
    (void)in_sizes; (void)n_in; (void)d_ws; (void)ws_size; (void)out_size;
    const float2* x = (const float2*)d_in[0];
    float2*       y = (float2*)d_out;

    const int total_threads = Bc * NC * DP;     // 131072
    dim3 grid(total_threads / 256), block(256);
    hipLaunchKernelGGL(ema_f32_kernel, grid, block, 0, stream, x, y);
}